// Round 6
// baseline (88.067 us; speedup 1.0000x reference)
//
#include <hip/hip_runtime.h>

// Additive RQ kernel, symmetric: covar[i,j] = os * sum_d (1 + ((x_i,d-x_j,d)/l_d)^2/(2a))^(-a)
// Output layout: [ mean (N floats, zeros) | covar (N*N floats) ]
// Upper-triangle 32x32 tiles; mirror via LDS transpose.
//
// pow(t,-alpha) = 2^(-alpha*log2 t) computed ENTIRELY in full-rate VALU:
//   log2(t): e = (bits>>23) [bias folded into poly c0], m = mantissa|1.0 in [1,2),
//            cubic Chebyshev log2(m) (err ~8e-4), coeffs pre-scaled by -alpha.
//   2^u, u in [-16.8, +0.002]: f = u - floor(u), cubic Chebyshev 2^f (rel err ~1e-4),
//            exponent applied via float-bits + (floor << 23)  (v_lshl_add_u32).
// No clamps needed: t = fma(d,d,1) in [1, ~325] always normal; u <= ~+0.002.
// Per-term err ~1.1e-3, x32 worst case ~0.035 << 0.577 threshold.

#define D 32
#define TILE 32

__global__ __launch_bounds__(256) void rq_covar_sym_kernel(
    const float* __restrict__ x,
    const float* __restrict__ ls,
    const float* __restrict__ alpha_p,
    const float* __restrict__ os_p,
    float* __restrict__ mean_out,
    float* __restrict__ covar,
    int n, int ntiles)
{
    __shared__ float As[TILE][36];
    __shared__ float Bs[TILE][36];

    const int t = threadIdx.x;
    const int k = blockIdx.x;

    // fold mean zeroing into the first ceil(n/256) blocks
    {
        const int idx = k * 256 + t;
        if (idx < n) mean_out[idx] = 0.0f;
    }

    // closed-form upper-triangle decode (bi <= bj)
    const float nt = (float)ntiles;
    int bi = (int)(nt + 0.5f - sqrtf((nt + 0.5f) * (nt + 0.5f) - 2.0f * (float)k));
    while (bi > 0 && k < bi * ntiles - (bi * (bi - 1)) / 2) --bi;
    while (k >= (bi + 1) * ntiles - ((bi + 1) * bi) / 2) ++bi;
    const int bj = bi + (k - (bi * ntiles - (bi * (bi - 1)) / 2));

    const float alpha = alpha_p[0];
    const float oscale = os_p[0];
    const float nalpha = -alpha;
    const float rs2a = rsqrtf(2.0f * alpha);

    // log2(m) cubic on [1,2), truncated Chebyshev; pre-scaled by nalpha,
    // exponent bias -127 folded into c0.
    const float c3 = nalpha * 0.155451f;
    const float c2 = nalpha * -1.039280f;
    const float c1 = nalpha * 3.029269f;
    const float c0 = nalpha * (-2.145013f - 127.0f);
    // 2^f cubic on [0,1), truncated Chebyshev (rel err ~1.2e-4).
    const float e3 = 0.0790775f;
    const float e2 = 0.2245175f;
    const float e1 = 0.6963947f;
    const float e0 = 0.9998857f;

    // Stage tiles pre-scaled by 1/(l_d * sqrt(2a)).
    {
        const int row = t >> 3;
        const int q = (t & 7) * 4;
        const float4 lv = *reinterpret_cast<const float4*>(&ls[q]);
        const float4 a = *reinterpret_cast<const float4*>(&x[(size_t)(bi * TILE + row) * D + q]);
        const float4 b = *reinterpret_cast<const float4*>(&x[(size_t)(bj * TILE + row) * D + q]);
        const float w0 = rs2a / lv.x, w1 = rs2a / lv.y, w2 = rs2a / lv.z, w3 = rs2a / lv.w;
        As[row][q + 0] = a.x * w0;  Bs[row][q + 0] = b.x * w0;
        As[row][q + 1] = a.y * w1;  Bs[row][q + 1] = b.y * w1;
        As[row][q + 2] = a.z * w2;  Bs[row][q + 2] = b.z * w2;
        As[row][q + 3] = a.w * w3;  Bs[row][q + 3] = b.w * w3;
    }
    __syncthreads();

    const int c = t & 31;
    const int r0 = t >> 5;

    float bs[D];
#pragma unroll
    for (int q = 0; q < D; q += 4) {
        const float4 v = *reinterpret_cast<const float4*>(&Bs[c][q]);
        bs[q] = v.x; bs[q + 1] = v.y; bs[q + 2] = v.z; bs[q + 3] = v.w;
    }

    float acc[4];
#pragma unroll
    for (int kk = 0; kk < 4; ++kk) {
        const int r = r0 + kk * 8;
        float as[D];
#pragma unroll
        for (int q = 0; q < D; q += 4) {
            const float4 v = *reinterpret_cast<const float4*>(&As[r][q]);
            as[q] = v.x; as[q + 1] = v.y; as[q + 2] = v.z; as[q + 3] = v.w;
        }
        float s0 = 0.0f, s1 = 0.0f, s2 = 0.0f, s3 = 0.0f;
#pragma unroll
        for (int d = 0; d < D; d += 4) {
#pragma unroll
            for (int j = 0; j < 4; ++j) {
                const float diff = as[d + j] - bs[d + j];
                const float tv = fmaf(diff, diff, 1.0f);
                const unsigned bits = __float_as_uint(tv);
                const float ef = (float)(bits >> 23);   // e + 127 (bias in c0)
                const float m = __uint_as_float((bits & 0x7FFFFFu) | 0x3f800000u);
                float q1 = fmaf(c3, m, c2);
                q1 = fmaf(q1, m, c1);
                q1 = fmaf(q1, m, c0);
                const float u = fmaf(ef, nalpha, q1);   // = nalpha * log2(tv)
                const float ff = floorf(u);
                const float fr = u - ff;
                const int fi = (int)ff;
                float p = fmaf(e3, fr, e2);
                p = fmaf(p, fr, e1);
                p = fmaf(p, fr, e0);
                const float term = __uint_as_float(__float_as_uint(p) + ((unsigned)fi << 23));
                if (j == 0) s0 += term;
                else if (j == 1) s1 += term;
                else if (j == 2) s2 += term;
                else s3 += term;
            }
        }
        acc[kk] = oscale * ((s0 + s1) + (s2 + s3));
    }

    // direct (coalesced) write of own tile
#pragma unroll
    for (int kk = 0; kk < 4; ++kk) {
        const int r = r0 + kk * 8;
        covar[(size_t)(bi * TILE + r) * n + (bj * TILE + c)] = acc[kk];
    }

    // mirror write for off-diagonal tiles: transpose through LDS
    if (bi != bj) {
        __syncthreads();
#pragma unroll
        for (int kk = 0; kk < 4; ++kk) {
            As[r0 + kk * 8][c] = acc[kk];
        }
        __syncthreads();
#pragma unroll
        for (int kk = 0; kk < 4; ++kk) {
            const int rr = r0 + kk * 8;
            const float v = As[c][rr];
            covar[(size_t)(bj * TILE + rr) * n + (bi * TILE + c)] = v;
        }
    }
}

extern "C" void kernel_launch(void* const* d_in, const int* in_sizes, int n_in,
                              void* d_out, int out_size, void* d_ws, size_t ws_size,
                              hipStream_t stream) {
    const float* x = (const float*)d_in[0];
    const float* ls = (const float*)d_in[1];
    const float* alpha_p = (const float*)d_in[2];
    const float* os_p = (const float*)d_in[3];

    const int n = in_sizes[0] / D;       // 2048
    const int ntiles = n / TILE;         // 64
    const int nblocks = ntiles * (ntiles + 1) / 2;  // 2080

    float* mean_out = (float*)d_out;
    float* covar = (float*)d_out + n;

    rq_covar_sym_kernel<<<nblocks, 256, 0, stream>>>(x, ls, alpha_p, os_p,
                                                     mean_out, covar, n, ntiles);
}

// Round 7
// 85.708 us; speedup vs baseline: 1.0275x; 1.0275x over previous
//
#include <hip/hip_runtime.h>

// Additive RQ kernel, symmetric: covar[i,j] = os * sum_d (1 + ((x_i,d-x_j,d)/l_d)^2/(2a))^(-a)
// Output layout: [ mean (N floats, zeros) | covar (N*N floats) ]
// Upper-triangle 32x32 tiles; mirror via LDS transpose.
//
// pow(t,-a) via exponent/mantissa split -- NO cvt/floor/trans ops in inner loop:
//   t = m * 2^e  (m in [1,2))  =>  t^(-a) = m^(-a) * 2^(-a*e)
//   2^(-a*e): 160-entry LDS table indexed by raw exponent byte (only e in [127,136]
//             ever hit; <=32 live entries -> one word per bank -> conflict-free,
//             same-entry lanes broadcast).
//   m^(-a):   degree-7 interpolating poly in s = m-1.5, coefficients built once
//             per thread from 8 Chebyshev-node values via Newton divided
//             differences (runtime alpha; nodes/reciprocals compile-time).
// Inner loop: 15 full-rate VALU + 1 conflict-free ds_read. Per-term err <= 3e-4;
// x32 terms ~ 0.01 << 0.577 threshold.

#define D 32
#define TILE 32

#if __has_builtin(__builtin_amdgcn_exp2f)
#define EXP2F(x) __builtin_amdgcn_exp2f(x)
#else
#define EXP2F(x) exp2f(x)
#endif
#if __has_builtin(__builtin_amdgcn_logf)
#define LOG2F(x) __builtin_amdgcn_logf(x)
#else
#define LOG2F(x) __log2f(x)
#endif

__global__ __launch_bounds__(256) void rq_covar_sym_kernel(
    const float* __restrict__ x,
    const float* __restrict__ ls,
    const float* __restrict__ alpha_p,
    const float* __restrict__ os_p,
    float* __restrict__ mean_out,
    float* __restrict__ covar,
    int n, int ntiles)
{
    __shared__ float As[TILE][36];
    __shared__ float Bs[TILE][36];
    __shared__ float pow2tab[160];   // indexed by raw exponent byte (bits>>23)

    const int t = threadIdx.x;
    const int k = blockIdx.x;

    // fold mean zeroing into the first ceil(n/256) blocks
    {
        const int idx = k * 256 + t;
        if (idx < n) mean_out[idx] = 0.0f;
    }

    // closed-form upper-triangle decode (bi <= bj)
    const float nt = (float)ntiles;
    int bi = (int)(nt + 0.5f - sqrtf((nt + 0.5f) * (nt + 0.5f) - 2.0f * (float)k));
    while (bi > 0 && k < bi * ntiles - (bi * (bi - 1)) / 2) --bi;
    while (k >= (bi + 1) * ntiles - ((bi + 1) * bi) / 2) ++bi;
    const int bj = bi + (k - (bi * ntiles - (bi * (bi - 1)) / 2));

    const float alpha = alpha_p[0];
    const float oscale = os_p[0];
    const float nalpha = -alpha;
    const float rs2a = rsqrtf(2.0f * alpha);

    // 2^(nalpha * (e-127)) table; only entries 127..136 are ever read.
    for (int e = t; e < 160; e += 256)
        pow2tab[e] = EXP2F(nalpha * (float)(e - 127));

    // ---- build degree-7 poly for m^(-alpha) on [1,2), in s = m - 1.5 ----
    // Chebyshev nodes of [1,2]:
    const float Xc[8] = {1.990393f, 1.915735f, 1.777785f, 1.597545f,
                         1.402455f, 1.222215f, 1.084265f, 1.009607f};
    float dd[8];
#pragma unroll
    for (int i = 0; i < 8; ++i)
        dd[i] = EXP2F(nalpha * LOG2F(Xc[i]));   // node values X_i^(-alpha)
    // Newton divided differences (node gaps are compile-time constants)
#pragma unroll
    for (int j = 1; j < 8; ++j) {
#pragma unroll
        for (int i = 7; i >= 1; --i) {
            if (i >= j)
                dd[i] = (dd[i] - dd[i - 1]) * (1.0f / (Xc[i] - Xc[i - j]));
        }
    }
    // expand nested Newton form to monomial coeffs in s = m - 1.5
    float C[8] = {0.0f, 0.0f, 0.0f, 0.0f, 0.0f, 0.0f, 0.0f, 0.0f};
    C[0] = dd[7];
#pragma unroll
    for (int i = 6; i >= 0; --i) {
        const float yi = Xc[i] - 1.5f;
#pragma unroll
        for (int kk = 7; kk >= 1; --kk)
            C[kk] = fmaf(-yi, C[kk], C[kk - 1]);
        C[0] = fmaf(-yi, C[0], dd[i]);
    }

    // Stage tiles pre-scaled by 1/(l_d * sqrt(2a)).
    {
        const int row = t >> 3;
        const int q = (t & 7) * 4;
        const float4 lv = *reinterpret_cast<const float4*>(&ls[q]);
        const float4 a = *reinterpret_cast<const float4*>(&x[(size_t)(bi * TILE + row) * D + q]);
        const float4 b = *reinterpret_cast<const float4*>(&x[(size_t)(bj * TILE + row) * D + q]);
        const float w0 = rs2a / lv.x, w1 = rs2a / lv.y, w2 = rs2a / lv.z, w3 = rs2a / lv.w;
        As[row][q + 0] = a.x * w0;  Bs[row][q + 0] = b.x * w0;
        As[row][q + 1] = a.y * w1;  Bs[row][q + 1] = b.y * w1;
        As[row][q + 2] = a.z * w2;  Bs[row][q + 2] = b.z * w2;
        As[row][q + 3] = a.w * w3;  Bs[row][q + 3] = b.w * w3;
    }
    __syncthreads();

    const int c = t & 31;
    const int r0 = t >> 5;

    float bs[D];
#pragma unroll
    for (int q = 0; q < D; q += 4) {
        const float4 v = *reinterpret_cast<const float4*>(&Bs[c][q]);
        bs[q] = v.x; bs[q + 1] = v.y; bs[q + 2] = v.z; bs[q + 3] = v.w;
    }

    float acc[4];
#pragma unroll
    for (int kk = 0; kk < 4; ++kk) {
        const int r = r0 + kk * 8;
        float as[D];
#pragma unroll
        for (int q = 0; q < D; q += 4) {
            const float4 v = *reinterpret_cast<const float4*>(&As[r][q]);
            as[q] = v.x; as[q + 1] = v.y; as[q + 2] = v.z; as[q + 3] = v.w;
        }
        float s0 = 0.0f, s1 = 0.0f, s2 = 0.0f, s3 = 0.0f;
#pragma unroll
        for (int d = 0; d < D; d += 4) {
#pragma unroll
            for (int j = 0; j < 4; ++j) {
                const float diff = as[d + j] - bs[d + j];
                const float tv = fmaf(diff, diff, 1.0f);
                const unsigned bits = __float_as_uint(tv);
                const float pw = pow2tab[bits >> 23];                    // conflict-free gather
                const float m = __uint_as_float((bits & 0x7FFFFFu) | 0x3F800000u);
                const float sm = m - 1.5f;
                float p = fmaf(C[7], sm, C[6]);
                p = fmaf(p, sm, C[5]);
                p = fmaf(p, sm, C[4]);
                p = fmaf(p, sm, C[3]);
                p = fmaf(p, sm, C[2]);
                p = fmaf(p, sm, C[1]);
                p = fmaf(p, sm, C[0]);
                const float term_pw = pw;
                if (j == 0) s0 = fmaf(p, term_pw, s0);
                else if (j == 1) s1 = fmaf(p, term_pw, s1);
                else if (j == 2) s2 = fmaf(p, term_pw, s2);
                else s3 = fmaf(p, term_pw, s3);
            }
        }
        acc[kk] = oscale * ((s0 + s1) + (s2 + s3));
    }

    // direct (coalesced) write of own tile
#pragma unroll
    for (int kk = 0; kk < 4; ++kk) {
        const int r = r0 + kk * 8;
        covar[(size_t)(bi * TILE + r) * n + (bj * TILE + c)] = acc[kk];
    }

    // mirror write for off-diagonal tiles: transpose through LDS
    if (bi != bj) {
        __syncthreads();
#pragma unroll
        for (int kk = 0; kk < 4; ++kk) {
            As[r0 + kk * 8][c] = acc[kk];
        }
        __syncthreads();
#pragma unroll
        for (int kk = 0; kk < 4; ++kk) {
            const int rr = r0 + kk * 8;
            const float v = As[c][rr];
            covar[(size_t)(bj * TILE + rr) * n + (bi * TILE + c)] = v;
        }
    }
}

extern "C" void kernel_launch(void* const* d_in, const int* in_sizes, int n_in,
                              void* d_out, int out_size, void* d_ws, size_t ws_size,
                              hipStream_t stream) {
    const float* x = (const float*)d_in[0];
    const float* ls = (const float*)d_in[1];
    const float* alpha_p = (const float*)d_in[2];
    const float* os_p = (const float*)d_in[3];

    const int n = in_sizes[0] / D;       // 2048
    const int ntiles = n / TILE;         // 64
    const int nblocks = ntiles * (ntiles + 1) / 2;  // 2080

    float* mean_out = (float*)d_out;
    float* covar = (float*)d_out + n;

    rq_covar_sym_kernel<<<nblocks, 256, 0, stream>>>(x, ls, alpha_p, os_p,
                                                     mean_out, covar, n, ntiles);
}